// Round 4
// baseline (390.121 us; speedup 1.0000x reference)
//
#include <hip/hip_runtime.h>
#include <cstdint>
#include <cmath>

#define V_SIZE 50257
#define T_SIZE 2048
#define B_SIZE 512
#define CHUNKS 8
#define CHUNK_LEN ((V_SIZE + CHUNKS - 1) / CHUNKS)   // 6283
#define NTHR_A 256
#define NTHR_B 512
#define NWAVE_B (NTHR_B / 64)
#define CAP 512
#define SPEC_THRESH 10.0f
#define SPEC_MIN 80
#define KOFF 32.0f

// ws layout (floats): gZ[512] | gcnt[512](int) | gval[512*CAP] | gidx[512*CAP](int)
// total = 4096 + 2*512*CAP*4 bytes = ~2.1 MB

// ---------------- Kernel A: pure read stream ----------------
// No bitmap, no penalty, no max: softmax max cancels (K-offset form), and for
// rp>=1 penalty only lowers values so {pen>10} subset {raw>10} -> raw collect
// is a superset. Tail kernel verifies and falls back exactly if violated.
extern "C" __global__ __launch_bounds__(NTHR_A, 8)
void stream_kernel(const float* __restrict__ logits,
                   float* __restrict__ gZ, int* __restrict__ gcnt,
                   float* __restrict__ gval, int* __restrict__ gidx)
{
    const int row = blockIdx.y;
    const int tid = threadIdx.x;
    const size_t rowoff = (size_t)row * V_SIZE;
    const float* lrow = logits + rowoff;
    const int lo = blockIdx.x * CHUNK_LEN;
    const int hi = min(V_SIZE, lo + CHUNK_LEN);

    float lz = 0.0f;
    auto proc = [&](float x, int v) {
        lz += __expf(x - KOFF);                 // x <= ~20 -> no overflow
        if (x > SPEC_THRESH) {
            int p = atomicAdd(&gcnt[row], 1);
            if (p < CAP) {
                gval[(size_t)row * CAP + p] = x;
                gidx[(size_t)row * CAP + p] = v;
            }
        }
    };

    int a0 = lo + (int)((4u - ((unsigned)(rowoff + lo) & 3u)) & 3u);
    if (a0 > hi) a0 = hi;
    const int nv = (hi - a0) >> 2;
    const int t0 = a0 + nv * 4;
    if (tid < a0 - lo) proc(lrow[lo + tid], lo + tid);
    if (tid < hi - t0) proc(lrow[t0 + tid], t0 + tid);
    const float4* l4 = (const float4*)(lrow + a0);
    for (int i = tid; i < nv; i += NTHR_A) {
        float4 x4 = l4[i];
        int v = a0 + i * 4;
        proc(x4.x, v); proc(x4.y, v + 1); proc(x4.z, v + 2); proc(x4.w, v + 3);
    }

    __shared__ float red[NTHR_A / 64];
    for (int off = 32; off; off >>= 1) lz += __shfl_down(lz, off);
    if ((tid & 63) == 0) red[tid >> 6] = lz;
    __syncthreads();
    if (tid == 0) {
        float s = 0.0f;
        for (int i = 0; i < NTHR_A / 64; ++i) s += red[i];
        atomicAdd(&gZ[row], s);
    }
}

// ---------------- Kernel B: per-row tail ----------------
extern "C" __global__ __launch_bounds__(NTHR_B, 4)
void tail_kernel(const float* __restrict__ logits,
                 const int*   __restrict__ prev,
                 const float* __restrict__ rand_u,
                 const float* __restrict__ tempp,
                 const float* __restrict__ toppp,
                 const float* __restrict__ repp,
                 const float* __restrict__ gZ,
                 const int*   __restrict__ gcnt,
                 const float* __restrict__ gval,
                 const int*   __restrict__ gidx,
                 float* __restrict__ out)
{
    const int row  = blockIdx.x;
    const int tid  = threadIdx.x;
    const int lane = tid & 63;
    const int wid  = tid >> 6;

    __shared__ unsigned int bitmap[(V_SIZE + 31) / 32];
    __shared__ float cval[CAP];
    __shared__ int   cidx[CAP];
    __shared__ float rbuf[CAP];
    __shared__ float redf[NWAVE_B];
    __shared__ int   redi[NWAVE_B];
    __shared__ float sZf, sS;
    __shared__ int   sCnt, sSend, sGT;

    const float rp   = repp[0];
    const float topp = toppp[0];
    const float temp = fmaxf(tempp[0], 1e-5f);

    const size_t rowoff = (size_t)row * V_SIZE;
    const float* lrow = logits + rowoff;
    const float* urow = rand_u + rowoff;
    float*       orow = out + B_SIZE + rowoff;

    for (int i = tid; i < (V_SIZE + 31) / 32; i += NTHR_B) bitmap[i] = 0u;
    if (tid == 0) { sCnt = 0; sGT = 0; }
    __syncthreads();

    // prev bitmap + dedup Z-correction: dZ = sum exp(pen(x)-K) - exp(x-K)
    float dz = 0.0f;
    const int4* prow4 = (const int4*)(prev + (size_t)row * T_SIZE);
    auto corr = [&](int t) {
        unsigned m = 1u << (t & 31);
        unsigned old = atomicOr(&bitmap[((unsigned)t) >> 5], m);
        if (!(old & m)) {                        // first setter owns this token
            float x = lrow[t];
            float y = (x < 0.0f) ? x * rp : x / rp;
            dz += __expf(y - KOFF) - __expf(x - KOFF);
        }
    };
    for (int i = tid; i < T_SIZE / 4; i += NTHR_B) {
        int4 t = prow4[i];
        corr(t.x); corr(t.y); corr(t.z); corr(t.w);
    }
    {
        for (int off = 32; off; off >>= 1) dz += __shfl_down(dz, off);
        if (lane == 0) redf[wid] = dz;
    }
    __syncthreads();
    if (tid == 0) {
        float s = 0.0f;
        for (int i = 0; i < NWAVE_B; ++i) s += redf[i];
        sZf = gZ[row] + s;                       // Z in K-offset form (exact)
    }
    __syncthreads();
    const float Z = sZf;

    // load candidates, apply penalty, count penalized > 10
    const int cntg = gcnt[row];
    const int Craw = min(cntg, CAP);
    {
        int myGT = 0;
        for (int j = tid; j < Craw; j += NTHR_B) {
            float x = gval[(size_t)row * CAP + j];
            int   v = gidx[(size_t)row * CAP + j];
            if ((bitmap[((unsigned)v) >> 5] >> (v & 31)) & 1u)
                x = (x < 0.0f) ? x * rp : x / rp;
            cval[j] = x; cidx[j] = v;
            if (x > SPEC_THRESH) myGT++;
        }
        for (int off = 32; off; off >>= 1) myGT += __shfl_down(myGT, off);
        if (lane == 0) redi[wid] = myGT;
    }
    __syncthreads();
    if (tid == 0) {
        int s = 0;
        for (int i = 0; i < NWAVE_B; ++i) s += redi[i];
        sGT = s;
    }
    __syncthreads();

    // validity: candidate set must contain the full top region after penalty.
    // penalized<=raw (rp>=1), so if >=80 penalized candidates exceed 10, every
    // non-candidate (raw<=10 -> pen<=10) is below the 80th candidate. Else
    // exact bisection fallback on penalized values.
    const bool fb = (cntg < SPEC_MIN) || (cntg > CAP) ||
                    (sGT < SPEC_MIN) || (rp < 1.0f);
    int C;
    if (!fb) {
        C = Craw;
    } else {
        auto pen_at = [&](int v) {
            float x = lrow[v];
            if ((bitmap[((unsigned)v) >> 5] >> (v & 31)) & 1u)
                x = (x < 0.0f) ? x * rp : x / rp;
            return x;
        };
        auto count_pass = [&](float thr) -> int {
            __syncthreads();
            if (tid == 0) sCnt = 0;
            __syncthreads();
            int local = 0;
            for (int v = tid; v < V_SIZE; v += NTHR_B)
                if (pen_at(v) > thr) local++;
            if (local) atomicAdd(&sCnt, local);
            __syncthreads();
            return sCnt;
        };
        float a = -200.0f, b = 200.0f, thr = 0.0f;
        int c = 0;
        for (int it = 0; it < 40; ++it) {
            thr = 0.5f * (a + b);
            c = count_pass(thr);
            if (c < SPEC_MIN)      b = thr;
            else if (c > CAP)      a = thr;
            else break;
        }
        if (c < SPEC_MIN) thr = a;
        __syncthreads();
        if (tid == 0) sCnt = 0;
        __syncthreads();
        for (int v = tid; v < V_SIZE; v += NTHR_B) {
            float x = pen_at(v);
            if (x > thr) {
                int p = atomicAdd(&sCnt, 1);
                if (p < CAP) { cval[p] = x; cidx[p] = v; }
            }
        }
        __syncthreads();
        C = min(sCnt, CAP);
    }

    // bitonic sort: descending value, tie -> ascending index
    int n = 1; while (n < C) n <<= 1;
    for (int i = C + tid; i < n; i += NTHR_B) { cval[i] = -INFINITY; cidx[i] = 0x7FFFFFFF; }
    __syncthreads();
    for (int k = 2; k <= n; k <<= 1) {
        for (int j = k >> 1; j > 0; j >>= 1) {
            for (int i = tid; i < n; i += NTHR_B) {
                int l = i ^ j;
                if (l > i) {
                    float vi = cval[i], vl = cval[l];
                    int   ii = cidx[i], il = cidx[l];
                    bool lFirst = (vl > vi) || (vl == vi && il < ii);
                    bool asc = ((i & k) == 0);
                    if (lFirst == asc) {
                        cval[i] = vl; cval[l] = vi;
                        cidx[i] = il; cidx[l] = ii;
                    }
                }
            }
            __syncthreads();
        }
    }

    // serial decision: top-p prefix m, top-50 pivot tie-run e.
    // cum uses exp(x-K)/Z_K (max cancels). With C>=80 and distinct values the
    // loop always breaks by i ~ 50+ties, so support stays inside the sorted set.
    if (tid == 0) {
        float cum = 0.0f;
        int m = 0;
        float vp = cval[min(49, C - 1)];
        for (int i = 0; i < C; ++i) {
            cum += expf(cval[i] - KOFF) / Z;
            if (i > 0 && cum > topp) break;
            m = i;
            if (m >= 49 && cval[i] < vp) break;
        }
        int send;
        if (m >= 49) {
            int e = 49;
            while (e + 1 < C && cval[e + 1] == vp) ++e;
            send = (m < e) ? m : e;
        } else {
            send = m;
        }
        sSend = send;
    }
    __syncthreads();

    // final softmax over support (temperature), scatter probs, Gumbel argmax
    const int send = sSend;
    const float v0 = cval[0];
    for (int i = tid; i <= send; i += NTHR_B)
        rbuf[i] = expf(cval[i] / temp - v0 / temp);
    __syncthreads();
    if (tid == 0) {
        float S = 0.0f;
        for (int i = 0; i <= send; ++i) S += rbuf[i];
        sS = S;
    }
    __syncthreads();
    const float S = sS;

    float bestr = -1.0f;
    int   besti = 0x7FFFFFFF;
    for (int i = tid; i <= send; i += NTHR_B) {
        float p = rbuf[i] / S;
        int v = cidx[i];
        orow[v] = p;                             // memset zeroed the rest
        float q = -logf(urow[v]);
        float r = p / q;
        if (r > bestr || (r == bestr && v < besti)) { bestr = r; besti = v; }
    }
    for (int off = 32; off; off >>= 1) {
        float r2 = __shfl_down(bestr, off);
        int   i2 = __shfl_down(besti, off);
        if (r2 > bestr || (r2 == bestr && i2 < besti)) { bestr = r2; besti = i2; }
    }
    if (lane == 0) { redf[wid] = bestr; redi[wid] = besti; }
    __syncthreads();
    if (tid == 0) {
        float br = redf[0]; int bi = redi[0];
        for (int i = 1; i < NWAVE_B; ++i) {
            if (redf[i] > br || (redf[i] == br && redi[i] < bi)) { br = redf[i]; bi = redi[i]; }
        }
        out[row] = (float)bi;
    }
}

extern "C" void kernel_launch(void* const* d_in, const int* in_sizes, int n_in,
                              void* d_out, int out_size, void* d_ws, size_t ws_size,
                              hipStream_t stream) {
    const float* logits = (const float*)d_in[0];
    const int*   prev   = (const int*)d_in[1];
    const float* rand_u = (const float*)d_in[2];
    const float* tempp  = (const float*)d_in[3];
    const float* toppp  = (const float*)d_in[4];
    const float* repp   = (const float*)d_in[5];
    float* out = (float*)d_out;

    float* gZ   = (float*)d_ws;
    int*   gcnt = (int*)d_ws + B_SIZE;
    float* gval = (float*)d_ws + 2 * B_SIZE;
    int*   gidx = (int*)d_ws + 2 * B_SIZE + B_SIZE * CAP;

    // zero output (probs default 0) and the ws accumulators (ws is poisoned)
    hipMemsetAsync(d_out, 0, (size_t)out_size * sizeof(float), stream);
    hipMemsetAsync(d_ws, 0, 2 * B_SIZE * sizeof(float), stream);

    hipLaunchKernelGGL(stream_kernel, dim3(CHUNKS, B_SIZE), dim3(NTHR_A), 0, stream,
                       logits, gZ, gcnt, gval, gidx);
    hipLaunchKernelGGL(tail_kernel, dim3(B_SIZE), dim3(NTHR_B), 0, stream,
                       logits, prev, rand_u, tempp, toppp, repp,
                       gZ, gcnt, gval, gidx, out);
}

// Round 5
// 262.231 us; speedup vs baseline: 1.4877x; 1.4877x over previous
//
#include <hip/hip_runtime.h>
#include <cstdint>
#include <cmath>

#define V_SIZE 50257
#define T_SIZE 2048
#define B_SIZE 512
#define NTHR 1024
#define NWAVE (NTHR / 64)
#define CAP 512
#define SPEC_THRESH 10.0f
#define SPEC_MIN 80
#define KOFF 32.0f

extern "C" __global__ __launch_bounds__(NTHR, 8)
void decode_kernel(const float* __restrict__ logits,
                   const int*   __restrict__ prev,
                   const float* __restrict__ rand_u,
                   const float* __restrict__ tempp,
                   const float* __restrict__ toppp,
                   const float* __restrict__ repp,
                   float* __restrict__ out)
{
    const int row  = blockIdx.x;
    const int tid  = threadIdx.x;
    const int lane = tid & 63;
    const int wid  = tid >> 6;

    __shared__ unsigned int bitmap[(V_SIZE + 31) / 32];   // 1571 words
    __shared__ float cval[CAP];
    __shared__ int   cidx[CAP];
    __shared__ float rbuf[CAP];
    __shared__ float redf[NWAVE];
    __shared__ int   redi[NWAVE];
    __shared__ float sZ, sS;
    __shared__ int   sCnt, sSend, sGT;

    const float rp   = repp[0];
    const float topp = toppp[0];
    const float temp = fmaxf(tempp[0], 1e-5f);

    const size_t rowoff = (size_t)row * V_SIZE;
    const float* lrow = logits + rowoff;
    const float* urow = rand_u + rowoff;
    float*       orow = out + B_SIZE + rowoff;

    for (int i = tid; i < (V_SIZE + 31) / 32; i += NTHR) bitmap[i] = 0u;
    if (tid == 0) { sCnt = 0; sGT = 0; }
    __syncthreads();

    // ---- phase 1: lean read stream. No bitmap/penalty (raw {x>10} is a
    //      verified superset for rp>=1), no max (K-offset form). 4x-unrolled
    //      float4 loads for staged vmcnt pipelining. ----
    const int head  = (4 - (row & 3)) & 3;      // V%4==1 -> rowoff%4 == row%4
    const int nvec  = (V_SIZE - head) >> 2;
    const int tails = head + nvec * 4;
    const float4* l4 = (const float4*)(lrow + head);

    float lz0 = 0.0f, lz1 = 0.0f;
    auto proc = [&](float x, int v, float& acc) {
        acc += __expf(x - KOFF);                // x <= ~20 -> no overflow
        if (x > SPEC_THRESH) {
            int p = atomicAdd(&sCnt, 1);
            if (p < CAP) { cval[p] = x; cidx[p] = v; }
        }
    };
    if (tid < head)           proc(lrow[tid], tid, lz0);
    if (tid < V_SIZE - tails) proc(lrow[tails + tid], tails + tid, lz1);

    auto proc4 = [&](float4 x4, int v) {
        proc(x4.x, v,     lz0); proc(x4.y, v + 1, lz1);
        proc(x4.z, v + 2, lz0); proc(x4.w, v + 3, lz1);
    };
    int i = tid;
    for (; i + 3 * NTHR < nvec; i += 4 * NTHR) {
        float4 a = l4[i];
        float4 b = l4[i + NTHR];
        float4 c = l4[i + 2 * NTHR];
        float4 d = l4[i + 3 * NTHR];
        proc4(a, head + i * 4);
        proc4(b, head + (i + NTHR) * 4);
        proc4(c, head + (i + 2 * NTHR) * 4);
        proc4(d, head + (i + 3 * NTHR) * 4);
    }
    for (; i < nvec; i += NTHR) {
        float4 a = l4[i];
        proc4(a, head + i * 4);
    }

    // ---- phase 2 (no barrier needed vs phase 1: disjoint LDS): prev-token
    //      bitmap + dedup Z-correction dz = sum exp(pen(x)-K) - exp(x-K) ----
    float dz = 0.0f;
    const int4* prow4 = (const int4*)(prev + (size_t)row * T_SIZE);
    auto corr = [&](int t) {
        unsigned m = 1u << (t & 31);
        unsigned old = atomicOr(&bitmap[((unsigned)t) >> 5], m);
        if (!(old & m)) {                        // first setter owns this token
            float x = lrow[t];
            float y = (x < 0.0f) ? x * rp : x / rp;
            dz += __expf(y - KOFF) - __expf(x - KOFF);
        }
    };
    for (int j = tid; j < T_SIZE / 4; j += NTHR) {
        int4 t = prow4[j];
        corr(t.x); corr(t.y); corr(t.z); corr(t.w);
    }

    // ---- single combined reduction: Z = sum(lz) + sum(dz), K-offset form ----
    {
        float wz = lz0 + lz1 + dz;
        for (int off = 32; off; off >>= 1) wz += __shfl_down(wz, off);
        if (lane == 0) redf[wid] = wz;
    }
    __syncthreads();                             // also orders bitmap + collect
    if (tid == 0) {
        float s = 0.0f;
        for (int j = 0; j < NWAVE; ++j) s += redf[j];
        sZ = s;
    }
    __syncthreads();
    const float Z = sZ;

    // ---- phase 3: penalize candidates via bitmap, count penalized > 10 ----
    const int cntg = sCnt;
    const int Craw = min(cntg, CAP);
    {
        int myGT = 0;
        for (int j = tid; j < Craw; j += NTHR) {
            float x = cval[j];
            int   v = cidx[j];
            if ((bitmap[((unsigned)v) >> 5] >> (v & 31)) & 1u) {
                x = (x < 0.0f) ? x * rp : x / rp;
                cval[j] = x;
            }
            if (x > SPEC_THRESH) myGT++;
        }
        for (int off = 32; off; off >>= 1) myGT += __shfl_down(myGT, off);
        if (lane == 0) redi[wid] = myGT;
    }
    __syncthreads();
    if (tid == 0) {
        int s = 0;
        for (int j = 0; j < NWAVE; ++j) s += redi[j];
        sGT = s;
    }
    __syncthreads();

    // validity: pen<=raw (rp>=1), so candidates = ALL {raw>10} superset of
    // {pen>10}; if >=80 candidates have pen>10, the sorted prefix down to
    // value 10 is complete+correct and the decision never leaves it.
    const bool fb = (cntg < SPEC_MIN) || (cntg > CAP) ||
                    (sGT < SPEC_MIN) || (rp < 1.0f);
    int C;
    if (!fb) {
        C = Craw;
    } else {
        auto pen_at = [&](int v) {
            float x = lrow[v];
            if ((bitmap[((unsigned)v) >> 5] >> (v & 31)) & 1u)
                x = (x < 0.0f) ? x * rp : x / rp;
            return x;
        };
        auto count_pass = [&](float thr) -> int {
            __syncthreads();
            if (tid == 0) sCnt = 0;
            __syncthreads();
            int local = 0;
            for (int v = tid; v < V_SIZE; v += NTHR)
                if (pen_at(v) > thr) local++;
            if (local) atomicAdd(&sCnt, local);
            __syncthreads();
            return sCnt;
        };
        float a = -200.0f, b = 200.0f, thr = 0.0f;
        int c = 0;
        for (int it = 0; it < 40; ++it) {
            thr = 0.5f * (a + b);
            c = count_pass(thr);
            if (c < SPEC_MIN)      b = thr;
            else if (c > CAP)      a = thr;
            else break;
        }
        if (c < SPEC_MIN) thr = a;
        __syncthreads();
        if (tid == 0) sCnt = 0;
        __syncthreads();
        for (int v = tid; v < V_SIZE; v += NTHR) {
            float x = pen_at(v);
            if (x > thr) {
                int p = atomicAdd(&sCnt, 1);
                if (p < CAP) { cval[p] = x; cidx[p] = v; }
            }
        }
        __syncthreads();
        C = min(sCnt, CAP);
    }

    // ---- bitonic sort: descending value, tie -> ascending index ----
    int n = 1; while (n < C) n <<= 1;
    for (int j = C + tid; j < n; j += NTHR) { cval[j] = -INFINITY; cidx[j] = 0x7FFFFFFF; }
    __syncthreads();
    for (int k = 2; k <= n; k <<= 1) {
        for (int j = k >> 1; j > 0; j >>= 1) {
            for (int p = tid; p < n; p += NTHR) {
                int l = p ^ j;
                if (l > p) {
                    float vi = cval[p], vl = cval[l];
                    int   ii = cidx[p], il = cidx[l];
                    bool lFirst = (vl > vi) || (vl == vi && il < ii);
                    bool asc = ((p & k) == 0);
                    if (lFirst == asc) {
                        cval[p] = vl; cval[l] = vi;
                        cidx[p] = il; cidx[l] = ii;
                    }
                }
            }
            __syncthreads();
        }
    }

    // ---- serial decision: top-p prefix m, top-50 pivot tie-run e ----
    if (tid == 0) {
        float cum = 0.0f;
        int m = 0;
        float vp = cval[min(49, C - 1)];
        for (int j = 0; j < C; ++j) {
            cum += expf(cval[j] - KOFF) / Z;
            if (j > 0 && cum > topp) break;
            m = j;
            if (m >= 49 && cval[j] < vp) break;
        }
        int send;
        if (m >= 49) {
            int e = 49;
            while (e + 1 < C && cval[e + 1] == vp) ++e;
            send = (m < e) ? m : e;
        } else {
            send = m;
        }
        sSend = send;
    }
    __syncthreads();

    // ---- final softmax over support (temperature), scatter, Gumbel argmax ----
    const int send = sSend;
    const float v0 = cval[0];
    for (int j = tid; j <= send; j += NTHR)
        rbuf[j] = expf(cval[j] / temp - v0 / temp);
    __syncthreads();
    if (tid == 0) {
        float S = 0.0f;
        for (int j = 0; j <= send; ++j) S += rbuf[j];
        sS = S;
    }
    __syncthreads();
    const float S = sS;

    float bestr = -1.0f;
    int   besti = 0x7FFFFFFF;
    for (int j = tid; j <= send; j += NTHR) {
        float p = rbuf[j] / S;
        int v = cidx[j];
        orow[v] = p;                             // memset zeroed the rest
        float q = -logf(urow[v]);
        float r = p / q;
        if (r > bestr || (r == bestr && v < besti)) { bestr = r; besti = v; }
    }
    for (int off = 32; off; off >>= 1) {
        float r2 = __shfl_down(bestr, off);
        int   i2 = __shfl_down(besti, off);
        if (r2 > bestr || (r2 == bestr && i2 < besti)) { bestr = r2; besti = i2; }
    }
    if (lane == 0) { redf[wid] = bestr; redi[wid] = besti; }
    __syncthreads();
    if (tid == 0) {
        float br = redf[0]; int bi = redi[0];
        for (int j = 1; j < NWAVE; ++j) {
            if (redf[j] > br || (redf[j] == br && redi[j] < bi)) { br = redf[j]; bi = redi[j]; }
        }
        out[row] = (float)bi;
    }
}

extern "C" void kernel_launch(void* const* d_in, const int* in_sizes, int n_in,
                              void* d_out, int out_size, void* d_ws, size_t ws_size,
                              hipStream_t stream) {
    const float* logits = (const float*)d_in[0];
    const int*   prev   = (const int*)d_in[1];
    const float* rand_u = (const float*)d_in[2];
    const float* tempp  = (const float*)d_in[3];
    const float* toppp  = (const float*)d_in[4];
    const float* repp   = (const float*)d_in[5];
    float* out = (float*)d_out;

    hipMemsetAsync(d_out, 0, (size_t)out_size * sizeof(float), stream);
    hipLaunchKernelGGL(decode_kernel, dim3(B_SIZE), dim3(NTHR), 0, stream,
                       logits, prev, rand_u, tempp, toppp, repp, out);
}